// Round 21
// baseline (199.210 us; speedup 1.0000x reference)
//
#include <hip/hip_runtime.h>
#include <hip/hip_bf16.h>

#define B_ 32
#define T_ 2048
#define H_ 1024
#define S_ 8
#define V_ 32768
#define ROWS 256    // B_*S_
#define OUTO 8192   // S_*H_
#define NCHUNK 64
#define TCHUNK 32
#define NCB 512     // dist col-blocks = V_/64
#define DELTA2 0.008f
#define MAXCAND 512

typedef __attribute__((ext_vector_type(8))) short s16x8;
typedef __attribute__((ext_vector_type(8))) unsigned short u16x8;
typedef __attribute__((ext_vector_type(4))) float f32x4;

__device__ __forceinline__ unsigned short bf16hi(float x) {
  return __builtin_bit_cast(unsigned short, __float2bfloat16(x));
}

// ---------------- kernel 1: masked pooling partials ----------------
__global__ void pool_kernel(const float* __restrict__ hidden,
                            const int* __restrict__ mask,
                            float* __restrict__ part_pool,   // [NCHUNK][B_][H_]
                            int* __restrict__ cntpart) {     // [NCHUNK][B_]
  int b = blockIdx.x;
  int chunk = blockIdx.y;
  int t0 = chunk * TCHUNK;
  int h4 = threadIdx.x * 4;
  const float* base = hidden + ((size_t)b * T_ + t0) * H_ + h4;
  const int* mrow = mask + (size_t)b * T_ + t0;
  float a0 = 0.f, a1 = 0.f, a2 = 0.f, a3 = 0.f;
  int mcount = 0;
#pragma unroll 4
  for (int i = 0; i < TCHUNK; ++i) {
    int mi = mrow[i];
    float m = (float)mi;
    mcount += mi;
    float4 v = *reinterpret_cast<const float4*>(base + (size_t)i * H_);
    a0 += m * v.x; a1 += m * v.y; a2 += m * v.z; a3 += m * v.w;
  }
  float* pp = part_pool + ((size_t)chunk * B_ + b) * H_ + h4;
  *reinterpret_cast<float4*>(pp) = make_float4(a0, a1, a2, a3);
  if (threadIdx.x == 0) cntpart[chunk * B_ + b] = mcount;
}

// ---------------- kernel 1b: reduce partials -> pooledT [h][b] ----------------
__global__ void pool_reduce_kernel(const float* __restrict__ part_pool,
                                   const int* __restrict__ cntpart,
                                   float* __restrict__ pooledT,
                                   int* __restrict__ cnt) {
  int g = blockIdx.x * 256 + threadIdx.x;   // g = b*1024 + h
  float s = 0.f;
  for (int c = 0; c < NCHUNK; ++c) s += part_pool[(size_t)c * (H_ * B_) + g];
  int b = g >> 10, h = g & 1023;
  pooledT[h * B_ + b] = s;
  if (g < B_) {
    int cs = 0;
    for (int c = 0; c < NCHUNK; ++c) cs += cntpart[c * B_ + g];
    cnt[g] = cs;
  }
}

// ---------------- kernel 2: pre_q = pooled @ W^T (R14 version) ----------------
__global__ __launch_bounds__(256) void proj_kernel(const float* __restrict__ Wp,
                            const float* __restrict__ pooledT,
                            const int* __restrict__ cnt,
                            float* __restrict__ preq) {
  __shared__ float pl[32][260];   // [b][k_local], 33 KB
  const int t = threadIdx.x;
  const int og = t >> 5, b = t & 31;
  const int o = blockIdx.x * 8 + og;
  const float* wrow = Wp + (size_t)o * H_;
  float acc = 0.f;
  for (int pass = 0; pass < 4; ++pass) {
    int k0 = pass * 256;
    __syncthreads();
#pragma unroll
    for (int i = 0; i < 8; ++i) {
      int f = i * 1024 + t * 4;            // 0..8191 over (k_local, b)
      int hl = f >> 5, b4 = f & 31;
      float4 v = *reinterpret_cast<const float4*>(&pooledT[(size_t)(k0 + hl) * 32 + b4]);
      pl[b4 + 0][hl] = v.x; pl[b4 + 1][hl] = v.y;
      pl[b4 + 2][hl] = v.z; pl[b4 + 3][hl] = v.w;
    }
    __syncthreads();
    const float* w0 = wrow + k0;
#pragma unroll 8
    for (int j = 0; j < 64; ++j) {
      float4 p = *reinterpret_cast<const float4*>(&pl[b][4 * j]);
      float4 a = *reinterpret_cast<const float4*>(w0 + 4 * j);
      acc += a.x * p.x + a.y * p.y + a.z * p.z + a.w * p.w;
    }
  }
  float denom = fmaxf((float)cnt[b], 1.0f);
  preq[(size_t)b * OUTO + o] = acc / denom;
}

// ---------------- kernel 2b: preq -> hi-bf16 image (linear) + xnorm ----------------
__global__ void aprep_kernel(const float* __restrict__ preq,
                             unsigned short* __restrict__ A_img,
                             float* __restrict__ xnorm) {
  int row = blockIdx.x;
  int t = threadIdx.x;
  int k0 = 4 * t;
  int ks = k0 >> 5, kk = k0 & 31;
  float4 v = reinterpret_cast<const float4*>(preq + (size_t)row * H_)[t];
  float xv[4] = {v.x, v.y, v.z, v.w};
  unsigned short hv[4];
  float s = 0.f;
#pragma unroll
  for (int i = 0; i < 4; ++i) { s += xv[i] * xv[i]; hv[i] = bf16hi(xv[i]); }
  *reinterpret_cast<ushort4*>(&A_img[(size_t)ks * 8192 + row * 32 + kk]) =
      make_ushort4(hv[0], hv[1], hv[2], hv[3]);
#pragma unroll
  for (int off = 1; off < 64; off <<= 1) s += __shfl_xor(s, off);
  __shared__ float ps[4];
  if ((t & 63) == 0) ps[t >> 6] = s;
  __syncthreads();
  if (t == 0) xnorm[row] = ps[0] + ps[1] + ps[2] + ps[3];
}

// ---------------- kernel 3: hi-only bf16 MFMA distance GEMM (BN=64, 2 blocks/CU) ----------------
// BM=256, BN=64, BK=32; 512 threads = 8 waves (4 m-groups x 2 n-halves of 32 cols),
// grid 512 -> TWO independent blocks/CU (launch_bounds(512,4) caps VGPR at 128;
// acc 32 + A 32 + cb 24 + misc ~ 120 fits). Two unsynchronized barrier groups per
// CU: one block's MFMA/issue phase covers the other's barrier drain (R15 warm-rep
// evidence: same structure at half latency runs 2.6x faster -> concurrency-bound).
// Keeps R18's 6-deep cb prefetch + lgkmcnt-only barrier.
__global__ __launch_bounds__(512, 4) void dist_kernel(
    const unsigned short* __restrict__ A_img, const float* __restrict__ codebook,
    const float* __restrict__ xnorm, float* __restrict__ logits,
    float* __restrict__ pscore) {
  __shared__ __align__(16) unsigned short Bs[2][64][40];    // 10 KB, pad 40
  __shared__ float cn[64];
  __shared__ float xns[256];
  __shared__ float bwv[2][256];

  const int t = threadIdx.x;        // 0..511
  const int l = t & 63;
  const int w = t >> 6;             // wave 0..7
  const int cb = w & 1;             // n-half (32 cols)
  const int m0 = (w >> 1) * 64;     // m-group (4 m-tiles)
  const int lr = l & 15, lq = l >> 4;
  const int blk = blockIdx.x;
  const int v0 = blk * 64;

  if (t < 256) xns[t] = xnorm[t];

  const int sn = t >> 3;            // staged codebook row 0..63
  const int sk = (t & 7) * 4;       // k offset within 32 (floats)
  const float* cbp = codebook + (size_t)(v0 + sn) * H_ + sk;
  float csq = 0.f;

  f32x4 acc[4][2];
#pragma unroll
  for (int i = 0; i < 4; ++i)
#pragma unroll
    for (int j = 0; j < 2; ++j) acc[i][j] = (f32x4){0.f, 0.f, 0.f, 0.f};

  unsigned int aoff[4];
#pragma unroll
  for (int mt = 0; mt < 4; ++mt)
    aoff[mt] = (unsigned int)((m0 + mt * 16 + lr) * 32 + lq * 8);

#define LOAD_A(DST, KS)                                                           \
  {                                                                               \
    int ka = (KS) > 31 ? 31 : (KS);                                               \
    _Pragma("unroll")                                                             \
    for (int mt = 0; mt < 4; ++mt)                                                \
      DST[mt] = *reinterpret_cast<const s16x8*>(&A_img[(size_t)ka * 8192 + aoff[mt]]); \
  }

#define LOAD_CB(DA, KS)                                                           \
  {                                                                               \
    int kl = (KS) > 31 ? 31 : (KS);                                               \
    DA = *reinterpret_cast<const float4*>(cbp + kl * 32);                         \
  }

#define CONV(BUF, X0)                                                             \
  {                                                                               \
    float xv[4] = {X0.x, X0.y, X0.z, X0.w};                                       \
    unsigned short hv[4];                                                         \
    _Pragma("unroll")                                                             \
    for (int i = 0; i < 4; ++i) { float x = xv[i]; csq += x * x; hv[i] = bf16hi(x); } \
    *reinterpret_cast<ushort4*>(&Bs[BUF][sn][sk]) =                               \
        make_ushort4(hv[0], hv[1], hv[2], hv[3]);                                 \
  }

#define BAR()                                                                     \
  asm volatile("s_waitcnt lgkmcnt(0)" ::: "memory");                              \
  __builtin_amdgcn_s_barrier();                                                   \
  __builtin_amdgcn_sched_barrier(0);

  // Step KS: load A(KS+1) -> AN; load cb(KS+6) into freed buffer; ds_read B(KS);
  // 8 MFMA with AU; convert cb(KS+1) -> Bs[(KS+1)&1]; lgkmcnt-only barrier.
#define STEP(KS, AU, AN, LDc, CVc)                                                \
  {                                                                               \
    LOAD_A(AN, (KS) + 1);                                                         \
    LOAD_CB(LDc, (KS) + 6);                                                       \
    s16x8 bh[2];                                                                  \
    _Pragma("unroll")                                                             \
    for (int nt = 0; nt < 2; ++nt)                                                \
      bh[nt] = *reinterpret_cast<const s16x8*>(&Bs[(KS) & 1][cb * 32 + nt * 16 + lr][lq * 8]); \
    __builtin_amdgcn_s_setprio(1);                                                \
    _Pragma("unroll")                                                             \
    for (int mt = 0; mt < 4; ++mt)                                                \
      _Pragma("unroll")                                                           \
      for (int nt = 0; nt < 2; ++nt)                                              \
        acc[mt][nt] = __builtin_amdgcn_mfma_f32_16x16x32_bf16(AU[mt], bh[nt], acc[mt][nt], 0, 0, 0); \
    __builtin_amdgcn_s_setprio(0);                                                \
    CONV(((KS) + 1) & 1, CVc);                                                    \
    BAR();                                                                        \
  }

  // ---- prologue: A(0) -> a0; cb(0..5) -> c0..c5; convert cb(0) -> Bs[0] ----
  s16x8 a0[4], a1[4];
  float4 c0, c1, c2, c3, c4, c5;
  LOAD_A(a0, 0);
  LOAD_CB(c0, 0);
  LOAD_CB(c1, 1);
  LOAD_CB(c2, 2);
  LOAD_CB(c3, 3);
  LOAD_CB(c4, 4);
  LOAD_CB(c5, 5);
  CONV(0, c0);
  BAR();

  // ---- main loop: steps 0..29, 6-step unroll (cb slot = KS%6, A alternates) ----
#pragma unroll 1
  for (int ks = 0; ks < 30; ks += 6) {
    STEP(ks + 0, a0, a1, c0, c1);
    STEP(ks + 1, a1, a0, c1, c2);
    STEP(ks + 2, a0, a1, c2, c3);
    STEP(ks + 3, a1, a0, c3, c4);
    STEP(ks + 4, a0, a1, c4, c5);
    STEP(ks + 5, a1, a0, c5, c0);
  }
  // ---- peel step 30: a0 = A(30) (loaded step 29); convert cb(31)=c1 (loaded step 25) ----
  {
    LOAD_A(a1, 31);
    s16x8 bh[2];
#pragma unroll
    for (int nt = 0; nt < 2; ++nt)
      bh[nt] = *reinterpret_cast<const s16x8*>(&Bs[0][cb * 32 + nt * 16 + lr][lq * 8]);
    __builtin_amdgcn_s_setprio(1);
#pragma unroll
    for (int mt = 0; mt < 4; ++mt)
#pragma unroll
      for (int nt = 0; nt < 2; ++nt)
        acc[mt][nt] = __builtin_amdgcn_mfma_f32_16x16x32_bf16(a0[mt], bh[nt], acc[mt][nt], 0, 0, 0);
    __builtin_amdgcn_s_setprio(0);
    CONV(1, c1);
    BAR();
  }
  // ---- peel step 31: compute only ----
  {
    s16x8 bh[2];
#pragma unroll
    for (int nt = 0; nt < 2; ++nt)
      bh[nt] = *reinterpret_cast<const s16x8*>(&Bs[1][cb * 32 + nt * 16 + lr][lq * 8]);
    __builtin_amdgcn_s_setprio(1);
#pragma unroll
    for (int mt = 0; mt < 4; ++mt)
#pragma unroll
      for (int nt = 0; nt < 2; ++nt)
        acc[mt][nt] = __builtin_amdgcn_mfma_f32_16x16x32_bf16(a1[mt], bh[nt], acc[mt][nt], 0, 0, 0);
    __builtin_amdgcn_s_setprio(0);
  }

  // ||c||^2: reduce the 8 k-offset threads (consecutive lanes) of each staged row
  csq += __shfl_xor(csq, 1);
  csq += __shfl_xor(csq, 2);
  csq += __shfl_xor(csq, 4);
  if ((t & 7) == 0) cn[sn] = csq;
  __syncthreads();

  // epilogue: logits + per-row approx max over this block's 64 cols
  const float NEG = -3.402823466e38f;
#pragma unroll
  for (int mt = 0; mt < 4; ++mt) {
#pragma unroll
    for (int r = 0; r < 4; ++r) {
      int row = m0 + mt * 16 + lq * 4 + r;
      float xn = xns[row];
      float bs = NEG;
#pragma unroll
      for (int nt = 0; nt < 2; ++nt) {
        int col = cb * 32 + nt * 16 + lr;
        float sc = 2.f * acc[mt][nt][r] - cn[col];
        logits[(size_t)row * V_ + v0 + col] = sc - xn;
        bs = fmaxf(bs, sc);
      }
#pragma unroll
      for (int off = 1; off < 16; off <<= 1) bs = fmaxf(bs, __shfl_xor(bs, off));
      if (lr == 0) bwv[cb][row] = bs;
    }
  }
  __syncthreads();
  if (t < 256) pscore[(size_t)t * NCB + blk] = fmaxf(bwv[0][t], bwv[1][t]);
}

// ---------------- kernel 4: candidates + exact f64 rescore + gather/loss ----------------
__global__ __launch_bounds__(256) void finalize_kernel(
    const float* __restrict__ preq, const float* __restrict__ codebook,
    const float* __restrict__ logits, const float* __restrict__ xnorm,
    const float* __restrict__ pscore,
    float* __restrict__ out_idx, float* __restrict__ out_quant,
    float* __restrict__ lsum) {
  int row = blockIdx.x;
  int t = threadIdx.x;
  float bs0 = -3.402823466e38f;
  for (int p = t; p < NCB; p += 256) bs0 = fmaxf(bs0, pscore[(size_t)row * NCB + p]);
  float m = bs0;
#pragma unroll
  for (int off = 1; off < 64; off <<= 1) m = fmaxf(m, __shfl_xor(m, off));
  __shared__ float wm[4];
  if ((t & 63) == 0) wm[t >> 6] = m;
  __syncthreads();
  float M = fmaxf(fmaxf(wm[0], wm[1]), fmaxf(wm[2], wm[3]));
  float thr = M - xnorm[row] - DELTA2;
  __shared__ int cand[MAXCAND];
  __shared__ int ncand;
  if (t == 0) ncand = 0;
  __syncthreads();
  const float* lrow = logits + (size_t)row * V_;
#pragma unroll 4
  for (int it = 0; it < 32; ++it) {
    int c0 = it * 1024 + t * 4;
    float4 lg = *reinterpret_cast<const float4*>(lrow + c0);
    if (lg.x >= thr) { int p = atomicAdd(&ncand, 1); if (p < MAXCAND) cand[p] = c0; }
    if (lg.y >= thr) { int p = atomicAdd(&ncand, 1); if (p < MAXCAND) cand[p] = c0 + 1; }
    if (lg.z >= thr) { int p = atomicAdd(&ncand, 1); if (p < MAXCAND) cand[p] = c0 + 2; }
    if (lg.w >= thr) { int p = atomicAdd(&ncand, 1); if (p < MAXCAND) cand[p] = c0 + 3; }
  }
  __syncthreads();
  int total = ncand;
  const float* pr = preq + (size_t)row * H_;
  int idx;
  if (total <= MAXCAND) {
    __shared__ double sd[4];
    double best = -1.0e300; int bi = V_;
    for (int j = 0; j < total; ++j) {
      int c = cand[j];
      const float* cr = codebook + (size_t)c * H_;
      float4 cv = reinterpret_cast<const float4*>(cr)[t];
      float4 pv = reinterpret_cast<const float4*>(pr)[t];
      double p = (double)cv.x * (2.0 * (double)pv.x - (double)cv.x)
               + (double)cv.y * (2.0 * (double)pv.y - (double)cv.y)
               + (double)cv.z * (2.0 * (double)pv.z - (double)cv.z)
               + (double)cv.w * (2.0 * (double)pv.w - (double)cv.w);
#pragma unroll
      for (int off = 1; off < 64; off <<= 1) p += __shfl_xor(p, off);
      if ((t & 63) == 0) sd[t >> 6] = p;
      __syncthreads();
      double s = sd[0] + sd[1] + sd[2] + sd[3];
      if (s > best || (s == best && c < bi)) { best = s; bi = c; }
      __syncthreads();
    }
    idx = bi;
  } else {
    double best = -1.0e300; int bi = V_;
    for (int c = t; c < V_; c += 256) {
      const float* cr = codebook + (size_t)c * H_;
      double s = 0.0;
      for (int k = 0; k < H_; k += 4) {
        float4 cv = *reinterpret_cast<const float4*>(cr + k);
        float4 pv = *reinterpret_cast<const float4*>(pr + k);
        s += (double)cv.x * (2.0 * (double)pv.x - (double)cv.x)
           + (double)cv.y * (2.0 * (double)pv.y - (double)cv.y)
           + (double)cv.z * (2.0 * (double)pv.z - (double)cv.z)
           + (double)cv.w * (2.0 * (double)pv.w - (double)cv.w);
      }
      if (s > best || (s == best && c < bi)) { best = s; bi = c; }
    }
#pragma unroll
    for (int off = 1; off < 64; off <<= 1) {
      double os = __shfl_xor(best, off);
      int oi = __shfl_xor(bi, off);
      if (os > best || (os == best && oi < bi)) { best = os; bi = oi; }
    }
    __shared__ double fb[4]; __shared__ int fbi[4];
    if ((t & 63) == 0) { fb[t >> 6] = best; fbi[t >> 6] = bi; }
    __syncthreads();
    double b0 = fb[0]; int i0 = fbi[0];
    for (int wv = 1; wv < 4; ++wv)
      if (fb[wv] > b0 || (fb[wv] == b0 && fbi[wv] < i0)) { b0 = fb[wv]; i0 = fbi[wv]; }
    idx = i0;
  }
  if (t == 0) out_idx[row] = (float)idx;
  float4 e = reinterpret_cast<const float4*>(codebook + (size_t)idx * H_)[t];
  float4 p4 = reinterpret_cast<const float4*>(pr)[t];
  float4 q;
  q.x = p4.x + (e.x - p4.x); q.y = p4.y + (e.y - p4.y);
  q.z = p4.z + (e.z - p4.z); q.w = p4.w + (e.w - p4.w);
  reinterpret_cast<float4*>(out_quant)[row * 256 + t] = q;
  float dx = p4.x - e.x, dy = p4.y - e.y, dz = p4.z - e.z, dw = p4.w - e.w;
  float ls = dx * dx + dy * dy + dz * dz + dw * dw;
#pragma unroll
  for (int off = 1; off < 64; off <<= 1) ls += __shfl_xor(ls, off);
  __shared__ float lss[4];
  if ((t & 63) == 0) lss[t >> 6] = ls;
  __syncthreads();
  if (t == 0) lsum[row] = lss[0] + lss[1] + lss[2] + lss[3];
}

// ---------------- kernel 5: final losses ----------------
__global__ void loss_kernel(const float* __restrict__ lsum, float* __restrict__ out_loss) {
  int t = threadIdx.x;
  float s = lsum[t];
#pragma unroll
  for (int off = 1; off < 64; off <<= 1) s += __shfl_xor(s, off);
  __shared__ float a[4];
  if ((t & 63) == 0) a[t >> 6] = s;
  __syncthreads();
  if (t == 0) {
    float lv = (a[0] + a[1] + a[2] + a[3]) / (float)(ROWS * H_);
    out_loss[0] = lv; out_loss[1] = lv;
  }
}

extern "C" void kernel_launch(void* const* d_in, const int* in_sizes, int n_in,
                              void* d_out, int out_size, void* d_ws, size_t ws_size,
                              hipStream_t stream) {
  (void)in_sizes; (void)n_in; (void)out_size; (void)ws_size;
  const float* hidden   = (const float*)d_in[0];
  const int* mask       = (const int*)d_in[1];
  const float* Wp       = (const float*)d_in[2];
  const float* codebook = (const float*)d_in[3];

  float* out = (float*)d_out;
  float* out_logits = out;                        // 8388608
  float* out_idx    = out + 8388608;              // 256
  float* out_preq   = out_idx + 256;              // 262144
  float* out_quant  = out_preq + 262144;          // 262144
  float* out_loss   = out_quant + 262144;         // 2

  // Early scratch inside logits region (fully overwritten by dist_kernel later).
  float* part_pool = out_logits;                   // 64*32*1024 = 2097152 floats
  int*   cntpart   = (int*)(out_logits + 2097152); // 2048
  float* pooledT   = out_logits + 2099200;         // 32768
  int*   cnt       = (int*)(out_logits + 2131968); // 32

  // d_ws scratch (~1.05 MB)
  float* ws     = (float*)d_ws;
  float* xnorm  = ws;                              // 256
  float* pscore = ws + 256;                        // 256*512 = 131072
  float* lsum   = ws + 131328;                     // 256
  unsigned short* A_img = (unsigned short*)(ws + 131584);  // 512 KB

  pool_kernel<<<dim3(B_, NCHUNK), 256, 0, stream>>>(hidden, mask, part_pool, cntpart);
  pool_reduce_kernel<<<128, 256, 0, stream>>>(part_pool, cntpart, pooledT, cnt);
  proj_kernel<<<1024, 256, 0, stream>>>(Wp, pooledT, cnt, out_preq);
  aprep_kernel<<<ROWS, 256, 0, stream>>>(out_preq, A_img, xnorm);
  dist_kernel<<<NCB, 512, 0, stream>>>(A_img, codebook, xnorm, out_logits, pscore);
  finalize_kernel<<<ROWS, 256, 0, stream>>>(out_preq, codebook, out_logits, xnorm,
                                            pscore, out_idx, out_quant, lsum);
  loss_kernel<<<1, 256, 0, stream>>>(lsum, out_loss);
}

// Round 22
// 183.077 us; speedup vs baseline: 1.0881x; 1.0881x over previous
//
#include <hip/hip_runtime.h>
#include <hip/hip_bf16.h>

#define B_ 32
#define T_ 2048
#define H_ 1024
#define S_ 8
#define V_ 32768
#define ROWS 256    // B_*S_
#define OUTO 8192   // S_*H_
#define NCHUNK 64
#define TCHUNK 32
#define NCB 256     // dist col-blocks = V_/128
#define DELTA2 0.008f
#define MAXCAND 512

typedef __attribute__((ext_vector_type(8))) short s16x8;
typedef __attribute__((ext_vector_type(8))) unsigned short u16x8;
typedef __attribute__((ext_vector_type(4))) float f32x4;

__device__ __forceinline__ unsigned short bf16hi(float x) {
  return __builtin_bit_cast(unsigned short, __float2bfloat16(x));
}

// ---------------- kernel 1: masked pooling partials ----------------
__global__ void pool_kernel(const float* __restrict__ hidden,
                            const int* __restrict__ mask,
                            float* __restrict__ part_pool,   // [NCHUNK][B_][H_]
                            int* __restrict__ cntpart) {     // [NCHUNK][B_]
  int b = blockIdx.x;
  int chunk = blockIdx.y;
  int t0 = chunk * TCHUNK;
  int h4 = threadIdx.x * 4;
  const float* base = hidden + ((size_t)b * T_ + t0) * H_ + h4;
  const int* mrow = mask + (size_t)b * T_ + t0;
  float a0 = 0.f, a1 = 0.f, a2 = 0.f, a3 = 0.f;
  int mcount = 0;
#pragma unroll 4
  for (int i = 0; i < TCHUNK; ++i) {
    int mi = mrow[i];
    float m = (float)mi;
    mcount += mi;
    float4 v = *reinterpret_cast<const float4*>(base + (size_t)i * H_);
    a0 += m * v.x; a1 += m * v.y; a2 += m * v.z; a3 += m * v.w;
  }
  float* pp = part_pool + ((size_t)chunk * B_ + b) * H_ + h4;
  *reinterpret_cast<float4*>(pp) = make_float4(a0, a1, a2, a3);
  if (threadIdx.x == 0) cntpart[chunk * B_ + b] = mcount;
}

// ---------------- kernel 1b: reduce partials -> pooledT [h][b] ----------------
__global__ void pool_reduce_kernel(const float* __restrict__ part_pool,
                                   const int* __restrict__ cntpart,
                                   float* __restrict__ pooledT,
                                   int* __restrict__ cnt) {
  int g = blockIdx.x * 256 + threadIdx.x;   // g = b*1024 + h
  float s = 0.f;
  for (int c = 0; c < NCHUNK; ++c) s += part_pool[(size_t)c * (H_ * B_) + g];
  int b = g >> 10, h = g & 1023;
  pooledT[h * B_ + b] = s;
  if (g < B_) {
    int cs = 0;
    for (int c = 0; c < NCHUNK; ++c) cs += cntpart[c * B_ + g];
    cnt[g] = cs;
  }
}

// ---------------- kernel 2: pre_q = pooled @ W^T (v3: pad 264, 2 o/thread) ----------------
// Grid 512 x 256 threads. 8 thread-groups (t>>5) x 32 b; each group owns TWO o-rows
// (16 o/block). pl pad 264 -> lane-stride 8 banks = 4-way conflict (was 260 = 8-way).
// Each pl read feeds 8 FMAs (was 4) -> total LDS read traffic halved. W read once
// grid-wide. Per-output FMA order identical to R14 -> preq bitwise unchanged.
__global__ __launch_bounds__(256) void proj_kernel(const float* __restrict__ Wp,
                            const float* __restrict__ pooledT,
                            const int* __restrict__ cnt,
                            float* __restrict__ preq) {
  __shared__ float pl[32][264];   // [b][k_local], 33.8 KB
  const int t = threadIdx.x;
  const int og = t >> 5, b = t & 31;
  const int o = blockIdx.x * 16 + og * 2;
  const float* wrow0 = Wp + (size_t)o * H_;
  const float* wrow1 = Wp + (size_t)(o + 1) * H_;
  float acc0 = 0.f, acc1 = 0.f;
  for (int pass = 0; pass < 4; ++pass) {
    int k0 = pass * 256;
    __syncthreads();
    // stage 256 k x 32 b = 8192 floats; each thread does 8 float4 (over b) scatters
#pragma unroll
    for (int i = 0; i < 8; ++i) {
      int f = i * 1024 + t * 4;            // 0..8191 over (k_local, b)
      int hl = f >> 5, b4 = f & 31;
      float4 v = *reinterpret_cast<const float4*>(&pooledT[(size_t)(k0 + hl) * 32 + b4]);
      pl[b4 + 0][hl] = v.x; pl[b4 + 1][hl] = v.y;
      pl[b4 + 2][hl] = v.z; pl[b4 + 3][hl] = v.w;
    }
    __syncthreads();
    const float* w0 = wrow0 + k0;
    const float* w1 = wrow1 + k0;
#pragma unroll 8
    for (int j = 0; j < 64; ++j) {
      float4 p = *reinterpret_cast<const float4*>(&pl[b][4 * j]);
      float4 a = *reinterpret_cast<const float4*>(w0 + 4 * j);
      float4 c = *reinterpret_cast<const float4*>(w1 + 4 * j);
      acc0 += a.x * p.x + a.y * p.y + a.z * p.z + a.w * p.w;
      acc1 += c.x * p.x + c.y * p.y + c.z * p.z + c.w * p.w;
    }
  }
  float denom = fmaxf((float)cnt[b], 1.0f);
  size_t obase = (size_t)b * OUTO + o;
  preq[obase + 0] = acc0 / denom;
  preq[obase + 1] = acc1 / denom;
}

// ---------------- kernel 2b: preq -> hi-bf16 image (linear) + xnorm ----------------
__global__ void aprep_kernel(const float* __restrict__ preq,
                             unsigned short* __restrict__ A_img,
                             float* __restrict__ xnorm) {
  int row = blockIdx.x;
  int t = threadIdx.x;
  int k0 = 4 * t;
  int ks = k0 >> 5, kk = k0 & 31;
  float4 v = reinterpret_cast<const float4*>(preq + (size_t)row * H_)[t];
  float xv[4] = {v.x, v.y, v.z, v.w};
  unsigned short hv[4];
  float s = 0.f;
#pragma unroll
  for (int i = 0; i < 4; ++i) { s += xv[i] * xv[i]; hv[i] = bf16hi(xv[i]); }
  *reinterpret_cast<ushort4*>(&A_img[(size_t)ks * 8192 + row * 32 + kk]) =
      make_ushort4(hv[0], hv[1], hv[2], hv[3]);
#pragma unroll
  for (int off = 1; off < 64; off <<= 1) s += __shfl_xor(s, off);
  __shared__ float ps[4];
  if ((t & 63) == 0) ps[t >> 6] = s;
  __syncthreads();
  if (t == 0) xnorm[row] = ps[0] + ps[1] + ps[2] + ps[3];
}

// ---------------- kernel 3: hi-only bf16 MFMA distance GEMM (R18 version, best) ----------------
__global__ __launch_bounds__(512, 2) void dist_kernel(
    const unsigned short* __restrict__ A_img, const float* __restrict__ codebook,
    const float* __restrict__ xnorm, float* __restrict__ logits,
    float* __restrict__ pscore) {
  __shared__ __align__(16) unsigned short Bs[2][128][40];   // 20 KB, pad 40
  __shared__ float cn[128];
  __shared__ float xns[256];
  __shared__ float bwv[2][256];

  const int t = threadIdx.x;        // 0..511
  const int l = t & 63;
  const int w = t >> 6;             // wave 0..7
  const int cb = w & 1;             // col half
  const int m0 = (w >> 1) * 64;     // row group
  const int lr = l & 15, lq = l >> 4;
  const int blk = blockIdx.x;
  const int v0 = blk * 128;

  if (t < 256) xns[t] = xnorm[t];

  const int sn = t >> 2;            // staged codebook row 0..127
  const int sk = (t & 3) * 8;       // k offset within 32
  const float* cbp = codebook + (size_t)(v0 + sn) * H_ + sk;
  float csq = 0.f;

  f32x4 acc[4][4];
#pragma unroll
  for (int i = 0; i < 4; ++i)
#pragma unroll
    for (int j = 0; j < 4; ++j) acc[i][j] = (f32x4){0.f, 0.f, 0.f, 0.f};

  unsigned int aoff[4];
#pragma unroll
  for (int mt = 0; mt < 4; ++mt)
    aoff[mt] = (unsigned int)((m0 + mt * 16 + lr) * 32 + lq * 8);

#define LOAD_A(DST, KS)                                                           \
  {                                                                               \
    int ka = (KS) > 31 ? 31 : (KS);                                               \
    _Pragma("unroll")                                                             \
    for (int mt = 0; mt < 4; ++mt)                                                \
      DST[mt] = *reinterpret_cast<const s16x8*>(&A_img[(size_t)ka * 8192 + aoff[mt]]); \
  }

#define LOAD_CB(DA, DB, KS)                                                       \
  {                                                                               \
    int kl = (KS) > 31 ? 31 : (KS);                                               \
    DA = *reinterpret_cast<const float4*>(cbp + kl * 32);                         \
    DB = *reinterpret_cast<const float4*>(cbp + kl * 32 + 4);                     \
  }

#define CONV(BUF, X0, X1)                                                         \
  {                                                                               \
    float xv[8] = {X0.x, X0.y, X0.z, X0.w, X1.x, X1.y, X1.z, X1.w};               \
    u16x8 hv;                                                                     \
    _Pragma("unroll")                                                             \
    for (int i = 0; i < 8; ++i) { float x = xv[i]; csq += x * x; hv[i] = bf16hi(x); } \
    *reinterpret_cast<u16x8*>(&Bs[BUF][sn][sk]) = hv;                             \
  }

#define BAR()                                                                     \
  asm volatile("s_waitcnt lgkmcnt(0)" ::: "memory");                              \
  __builtin_amdgcn_s_barrier();                                                   \
  __builtin_amdgcn_sched_barrier(0);

#define STEP(KS, AU, AN, LDa, LDb, CVa, CVb)                                      \
  {                                                                               \
    LOAD_A(AN, (KS) + 1);                                                         \
    LOAD_CB(LDa, LDb, (KS) + 6);                                                  \
    s16x8 bh[4];                                                                  \
    _Pragma("unroll")                                                             \
    for (int nt = 0; nt < 4; ++nt)                                                \
      bh[nt] = *reinterpret_cast<const s16x8*>(&Bs[(KS) & 1][cb * 64 + nt * 16 + lr][lq * 8]); \
    __builtin_amdgcn_s_setprio(1);                                                \
    _Pragma("unroll")                                                             \
    for (int mt = 0; mt < 4; ++mt)                                                \
      _Pragma("unroll")                                                           \
      for (int nt = 0; nt < 4; ++nt)                                              \
        acc[mt][nt] = __builtin_amdgcn_mfma_f32_16x16x32_bf16(AU[mt], bh[nt], acc[mt][nt], 0, 0, 0); \
    __builtin_amdgcn_s_setprio(0);                                                \
    CONV(((KS) + 1) & 1, CVa, CVb);                                               \
    BAR();                                                                        \
  }

  // ---- prologue: A(0); cb(0..5) -> c0..c5; convert cb(0) -> Bs[0] ----
  s16x8 a0[4], a1[4];
  LOAD_A(a0, 0);
  float4 c0a, c0b, c1a, c1b, c2a, c2b, c3a, c3b, c4a, c4b, c5a, c5b;
  LOAD_CB(c0a, c0b, 0);
  LOAD_CB(c1a, c1b, 1);
  LOAD_CB(c2a, c2b, 2);
  LOAD_CB(c3a, c3b, 3);
  LOAD_CB(c4a, c4b, 4);
  LOAD_CB(c5a, c5b, 5);
  CONV(0, c0a, c0b);
  BAR();

  // ---- main loop: steps 0..29, 6-step unroll ----
#pragma unroll 1
  for (int ks = 0; ks < 30; ks += 6) {
    STEP(ks + 0, a0, a1, c0a, c0b, c1a, c1b);
    STEP(ks + 1, a1, a0, c1a, c1b, c2a, c2b);
    STEP(ks + 2, a0, a1, c2a, c2b, c3a, c3b);
    STEP(ks + 3, a1, a0, c3a, c3b, c4a, c4b);
    STEP(ks + 4, a0, a1, c4a, c4b, c5a, c5b);
    STEP(ks + 5, a1, a0, c5a, c5b, c0a, c0b);
  }
  // ---- peel step 30 ----
  {
    LOAD_A(a1, 31);
    s16x8 bh[4];
#pragma unroll
    for (int nt = 0; nt < 4; ++nt)
      bh[nt] = *reinterpret_cast<const s16x8*>(&Bs[0][cb * 64 + nt * 16 + lr][lq * 8]);
    __builtin_amdgcn_s_setprio(1);
#pragma unroll
    for (int mt = 0; mt < 4; ++mt)
#pragma unroll
      for (int nt = 0; nt < 4; ++nt)
        acc[mt][nt] = __builtin_amdgcn_mfma_f32_16x16x32_bf16(a0[mt], bh[nt], acc[mt][nt], 0, 0, 0);
    __builtin_amdgcn_s_setprio(0);
    CONV(1, c1a, c1b);
    BAR();
  }
  // ---- peel step 31 ----
  {
    s16x8 bh[4];
#pragma unroll
    for (int nt = 0; nt < 4; ++nt)
      bh[nt] = *reinterpret_cast<const s16x8*>(&Bs[1][cb * 64 + nt * 16 + lr][lq * 8]);
    __builtin_amdgcn_s_setprio(1);
#pragma unroll
    for (int mt = 0; mt < 4; ++mt)
#pragma unroll
      for (int nt = 0; nt < 4; ++nt)
        acc[mt][nt] = __builtin_amdgcn_mfma_f32_16x16x32_bf16(a1[mt], bh[nt], acc[mt][nt], 0, 0, 0);
    __builtin_amdgcn_s_setprio(0);
  }

  // ||c||^2: reduce the 4 k-offset threads of each staged row
  csq += __shfl_xor(csq, 1);
  csq += __shfl_xor(csq, 2);
  if ((t & 3) == 0) cn[sn] = csq;
  __syncthreads();

  const float NEG = -3.402823466e38f;
#pragma unroll
  for (int mt = 0; mt < 4; ++mt) {
#pragma unroll
    for (int r = 0; r < 4; ++r) {
      int row = m0 + mt * 16 + lq * 4 + r;
      float xn = xns[row];
      float bs = NEG;
#pragma unroll
      for (int nt = 0; nt < 4; ++nt) {
        int col = cb * 64 + nt * 16 + lr;
        float sc = 2.f * acc[mt][nt][r] - cn[col];
        logits[(size_t)row * V_ + v0 + col] = sc - xn;
        bs = fmaxf(bs, sc);
      }
#pragma unroll
      for (int off = 1; off < 16; off <<= 1) bs = fmaxf(bs, __shfl_xor(bs, off));
      if (lr == 0) bwv[cb][row] = bs;
    }
  }
  __syncthreads();
  if (t < 256) pscore[(size_t)t * NCB + blk] = fmaxf(bwv[0][t], bwv[1][t]);
}

// ---------------- kernel 4: candidates + exact f64 rescore + gather/loss ----------------
__global__ __launch_bounds__(256) void finalize_kernel(
    const float* __restrict__ preq, const float* __restrict__ codebook,
    const float* __restrict__ logits, const float* __restrict__ xnorm,
    const float* __restrict__ pscore,
    float* __restrict__ out_idx, float* __restrict__ out_quant,
    float* __restrict__ lsum) {
  int row = blockIdx.x;
  int t = threadIdx.x;
  float m = pscore[(size_t)row * NCB + t];
#pragma unroll
  for (int off = 1; off < 64; off <<= 1) m = fmaxf(m, __shfl_xor(m, off));
  __shared__ float wm[4];
  if ((t & 63) == 0) wm[t >> 6] = m;
  __syncthreads();
  float M = fmaxf(fmaxf(wm[0], wm[1]), fmaxf(wm[2], wm[3]));
  float thr = M - xnorm[row] - DELTA2;
  __shared__ int cand[MAXCAND];
  __shared__ int ncand;
  if (t == 0) ncand = 0;
  __syncthreads();
  const float* lrow = logits + (size_t)row * V_;
#pragma unroll 4
  for (int it = 0; it < 32; ++it) {
    int c0 = it * 1024 + t * 4;
    float4 lg = *reinterpret_cast<const float4*>(lrow + c0);
    if (lg.x >= thr) { int p = atomicAdd(&ncand, 1); if (p < MAXCAND) cand[p] = c0; }
    if (lg.y >= thr) { int p = atomicAdd(&ncand, 1); if (p < MAXCAND) cand[p] = c0 + 1; }
    if (lg.z >= thr) { int p = atomicAdd(&ncand, 1); if (p < MAXCAND) cand[p] = c0 + 2; }
    if (lg.w >= thr) { int p = atomicAdd(&ncand, 1); if (p < MAXCAND) cand[p] = c0 + 3; }
  }
  __syncthreads();
  int total = ncand;
  const float* pr = preq + (size_t)row * H_;
  int idx;
  if (total <= MAXCAND) {
    __shared__ double sd[4];
    double best = -1.0e300; int bi = V_;
    for (int j = 0; j < total; ++j) {
      int c = cand[j];
      const float* cr = codebook + (size_t)c * H_;
      float4 cv = reinterpret_cast<const float4*>(cr)[t];
      float4 pv = reinterpret_cast<const float4*>(pr)[t];
      double p = (double)cv.x * (2.0 * (double)pv.x - (double)cv.x)
               + (double)cv.y * (2.0 * (double)pv.y - (double)cv.y)
               + (double)cv.z * (2.0 * (double)pv.z - (double)cv.z)
               + (double)cv.w * (2.0 * (double)pv.w - (double)cv.w);
#pragma unroll
      for (int off = 1; off < 64; off <<= 1) p += __shfl_xor(p, off);
      if ((t & 63) == 0) sd[t >> 6] = p;
      __syncthreads();
      double s = sd[0] + sd[1] + sd[2] + sd[3];
      if (s > best || (s == best && c < bi)) { best = s; bi = c; }
      __syncthreads();
    }
    idx = bi;
  } else {
    double best = -1.0e300; int bi = V_;
    for (int c = t; c < V_; c += 256) {
      const float* cr = codebook + (size_t)c * H_;
      double s = 0.0;
      for (int k = 0; k < H_; k += 4) {
        float4 cv = *reinterpret_cast<const float4*>(cr + k);
        float4 pv = *reinterpret_cast<const float4*>(pr + k);
        s += (double)cv.x * (2.0 * (double)pv.x - (double)cv.x)
           + (double)cv.y * (2.0 * (double)pv.y - (double)cv.y)
           + (double)cv.z * (2.0 * (double)pv.z - (double)cv.z)
           + (double)cv.w * (2.0 * (double)pv.w - (double)cv.w);
      }
      if (s > best || (s == best && c < bi)) { best = s; bi = c; }
    }
#pragma unroll
    for (int off = 1; off < 64; off <<= 1) {
      double os = __shfl_xor(best, off);
      int oi = __shfl_xor(bi, off);
      if (os > best || (os == best && oi < bi)) { best = os; bi = oi; }
    }
    __shared__ double fb[4]; __shared__ int fbi[4];
    if ((t & 63) == 0) { fb[t >> 6] = best; fbi[t >> 6] = bi; }
    __syncthreads();
    double b0 = fb[0]; int i0 = fbi[0];
    for (int wv = 1; wv < 4; ++wv)
      if (fb[wv] > b0 || (fb[wv] == b0 && fbi[wv] < i0)) { b0 = fb[wv]; i0 = fbi[wv]; }
    idx = i0;
  }
  if (t == 0) out_idx[row] = (float)idx;
  float4 e = reinterpret_cast<const float4*>(codebook + (size_t)idx * H_)[t];
  float4 p4 = reinterpret_cast<const float4*>(pr)[t];
  float4 q;
  q.x = p4.x + (e.x - p4.x); q.y = p4.y + (e.y - p4.y);
  q.z = p4.z + (e.z - p4.z); q.w = p4.w + (e.w - p4.w);
  reinterpret_cast<float4*>(out_quant)[row * 256 + t] = q;
  float dx = p4.x - e.x, dy = p4.y - e.y, dz = p4.z - e.z, dw = p4.w - e.w;
  float ls = dx * dx + dy * dy + dz * dz + dw * dw;
#pragma unroll
  for (int off = 1; off < 64; off <<= 1) ls += __shfl_xor(ls, off);
  __shared__ float lss[4];
  if ((t & 63) == 0) lss[t >> 6] = ls;
  __syncthreads();
  if (t == 0) lsum[row] = lss[0] + lss[1] + lss[2] + lss[3];
}

// ---------------- kernel 5: final losses ----------------
__global__ void loss_kernel(const float* __restrict__ lsum, float* __restrict__ out_loss) {
  int t = threadIdx.x;
  float s = lsum[t];
#pragma unroll
  for (int off = 1; off < 64; off <<= 1) s += __shfl_xor(s, off);
  __shared__ float a[4];
  if ((t & 63) == 0) a[t >> 6] = s;
  __syncthreads();
  if (t == 0) {
    float lv = (a[0] + a[1] + a[2] + a[3]) / (float)(ROWS * H_);
    out_loss[0] = lv; out_loss[1] = lv;
  }
}

extern "C" void kernel_launch(void* const* d_in, const int* in_sizes, int n_in,
                              void* d_out, int out_size, void* d_ws, size_t ws_size,
                              hipStream_t stream) {
  (void)in_sizes; (void)n_in; (void)out_size; (void)ws_size;
  const float* hidden   = (const float*)d_in[0];
  const int* mask       = (const int*)d_in[1];
  const float* Wp       = (const float*)d_in[2];
  const float* codebook = (const float*)d_in[3];

  float* out = (float*)d_out;
  float* out_logits = out;                        // 8388608
  float* out_idx    = out + 8388608;              // 256
  float* out_preq   = out_idx + 256;              // 262144
  float* out_quant  = out_preq + 262144;          // 262144
  float* out_loss   = out_quant + 262144;         // 2

  // Early scratch inside logits region (fully overwritten by dist_kernel later).
  float* part_pool = out_logits;                   // 64*32*1024 = 2097152 floats
  int*   cntpart   = (int*)(out_logits + 2097152); // 2048
  float* pooledT   = out_logits + 2099200;         // 32768
  int*   cnt       = (int*)(out_logits + 2131968); // 32

  // d_ws scratch (~0.8 MB)
  float* ws     = (float*)d_ws;
  float* xnorm  = ws;                              // 256
  float* pscore = ws + 256;                        // 256*256
  float* lsum   = ws + 65792;                      // 256
  unsigned short* A_img = (unsigned short*)(ws + 66048);   // 512 KB

  pool_kernel<<<dim3(B_, NCHUNK), 256, 0, stream>>>(hidden, mask, part_pool, cntpart);
  pool_reduce_kernel<<<128, 256, 0, stream>>>(part_pool, cntpart, pooledT, cnt);
  proj_kernel<<<512, 256, 0, stream>>>(Wp, pooledT, cnt, out_preq);
  aprep_kernel<<<ROWS, 256, 0, stream>>>(out_preq, A_img, xnorm);
  dist_kernel<<<NCB, 512, 0, stream>>>(A_img, codebook, xnorm, out_logits, pscore);
  finalize_kernel<<<ROWS, 256, 0, stream>>>(out_preq, codebook, out_logits, xnorm,
                                            pscore, out_idx, out_quant, lsum);
  loss_kernel<<<1, 256, 0, stream>>>(lsum, out_loss);
}

// Round 24
// 163.419 us; speedup vs baseline: 1.2190x; 1.1203x over previous
//
#include <hip/hip_runtime.h>
#include <hip/hip_bf16.h>

#define B_ 32
#define T_ 2048
#define H_ 1024
#define S_ 8
#define V_ 32768
#define ROWS 256    // B_*S_
#define OUTO 8192   // S_*H_
#define NCHUNK 64
#define TCHUNK 32
#define NCB 256     // dist col-blocks = V_/128
#define DELTA2 0.008f
#define MAXCAND 512

typedef __attribute__((ext_vector_type(8))) short s16x8;
typedef __attribute__((ext_vector_type(8))) unsigned short u16x8;
typedef __attribute__((ext_vector_type(4))) float f32x4;

__device__ __forceinline__ unsigned short bf16hi(float x) {
  return __builtin_bit_cast(unsigned short, __float2bfloat16(x));
}

// ---------------- kernel 1: masked pooling partials (nontemporal hidden loads) ----------------
__global__ void pool_kernel(const float* __restrict__ hidden,
                            const int* __restrict__ mask,
                            float* __restrict__ part_pool,   // [NCHUNK][B_][H_]
                            int* __restrict__ cntpart) {     // [NCHUNK][B_]
  int b = blockIdx.x;
  int chunk = blockIdx.y;
  int t0 = chunk * TCHUNK;
  int h4 = threadIdx.x * 4;
  const float* base = hidden + ((size_t)b * T_ + t0) * H_ + h4;
  const int* mrow = mask + (size_t)b * T_ + t0;
  float a0 = 0.f, a1 = 0.f, a2 = 0.f, a3 = 0.f;
  int mcount = 0;
#pragma unroll 4
  for (int i = 0; i < TCHUNK; ++i) {
    int mi = mrow[i];
    float m = (float)mi;
    mcount += mi;
    f32x4 v = __builtin_nontemporal_load(
        reinterpret_cast<const f32x4*>(base + (size_t)i * H_));
    a0 += m * v.x; a1 += m * v.y; a2 += m * v.z; a3 += m * v.w;
  }
  float* pp = part_pool + ((size_t)chunk * B_ + b) * H_ + h4;
  *reinterpret_cast<float4*>(pp) = make_float4(a0, a1, a2, a3);
  if (threadIdx.x == 0) cntpart[chunk * B_ + b] = mcount;
}

// ---------------- kernel 1b: reduce partials -> pooledT [h][b] ----------------
__global__ void pool_reduce_kernel(const float* __restrict__ part_pool,
                                   const int* __restrict__ cntpart,
                                   float* __restrict__ pooledT,
                                   int* __restrict__ cnt) {
  int g = blockIdx.x * 256 + threadIdx.x;   // g = b*1024 + h
  float s = 0.f;
  for (int c = 0; c < NCHUNK; ++c) s += part_pool[(size_t)c * (H_ * B_) + g];
  int b = g >> 10, h = g & 1023;
  pooledT[h * B_ + b] = s;
  if (g < B_) {
    int cs = 0;
    for (int c = 0; c < NCHUNK; ++c) cs += cntpart[c * B_ + g];
    cnt[g] = cs;
  }
}

// ---------------- kernel 2: pre_q = pooled @ W^T (R22 v3: pad 264, 2 o/thread) ----------------
__global__ __launch_bounds__(256) void proj_kernel(const float* __restrict__ Wp,
                            const float* __restrict__ pooledT,
                            const int* __restrict__ cnt,
                            float* __restrict__ preq) {
  __shared__ float pl[32][264];   // [b][k_local], 33.8 KB
  const int t = threadIdx.x;
  const int og = t >> 5, b = t & 31;
  const int o = blockIdx.x * 16 + og * 2;
  const float* wrow0 = Wp + (size_t)o * H_;
  const float* wrow1 = Wp + (size_t)(o + 1) * H_;
  float acc0 = 0.f, acc1 = 0.f;
  for (int pass = 0; pass < 4; ++pass) {
    int k0 = pass * 256;
    __syncthreads();
#pragma unroll
    for (int i = 0; i < 8; ++i) {
      int f = i * 1024 + t * 4;            // 0..8191 over (k_local, b)
      int hl = f >> 5, b4 = f & 31;
      float4 v = *reinterpret_cast<const float4*>(&pooledT[(size_t)(k0 + hl) * 32 + b4]);
      pl[b4 + 0][hl] = v.x; pl[b4 + 1][hl] = v.y;
      pl[b4 + 2][hl] = v.z; pl[b4 + 3][hl] = v.w;
    }
    __syncthreads();
    const float* w0 = wrow0 + k0;
    const float* w1 = wrow1 + k0;
#pragma unroll 8
    for (int j = 0; j < 64; ++j) {
      float4 p = *reinterpret_cast<const float4*>(&pl[b][4 * j]);
      float4 a = *reinterpret_cast<const float4*>(w0 + 4 * j);
      float4 c = *reinterpret_cast<const float4*>(w1 + 4 * j);
      acc0 += a.x * p.x + a.y * p.y + a.z * p.z + a.w * p.w;
      acc1 += c.x * p.x + c.y * p.y + c.z * p.z + c.w * p.w;
    }
  }
  float denom = fmaxf((float)cnt[b], 1.0f);
  size_t obase = (size_t)b * OUTO + o;
  preq[obase + 0] = acc0 / denom;
  preq[obase + 1] = acc1 / denom;
}

// ---------------- kernel 2b: preq -> hi-bf16 image (linear) + xnorm ----------------
__global__ void aprep_kernel(const float* __restrict__ preq,
                             unsigned short* __restrict__ A_img,
                             float* __restrict__ xnorm) {
  int row = blockIdx.x;
  int t = threadIdx.x;
  int k0 = 4 * t;
  int ks = k0 >> 5, kk = k0 & 31;
  float4 v = reinterpret_cast<const float4*>(preq + (size_t)row * H_)[t];
  float xv[4] = {v.x, v.y, v.z, v.w};
  unsigned short hv[4];
  float s = 0.f;
#pragma unroll
  for (int i = 0; i < 4; ++i) { s += xv[i] * xv[i]; hv[i] = bf16hi(xv[i]); }
  *reinterpret_cast<ushort4*>(&A_img[(size_t)ks * 8192 + row * 32 + kk]) =
      make_ushort4(hv[0], hv[1], hv[2], hv[3]);
#pragma unroll
  for (int off = 1; off < 64; off <<= 1) s += __shfl_xor(s, off);
  __shared__ float ps[4];
  if ((t & 63) == 0) ps[t >> 6] = s;
  __syncthreads();
  if (t == 0) xnorm[row] = ps[0] + ps[1] + ps[2] + ps[3];
}

// ---------------- kernel 3: hi-only bf16 MFMA distance GEMM (R18 + nt logits stores) ----------------
__global__ __launch_bounds__(512, 2) void dist_kernel(
    const unsigned short* __restrict__ A_img, const float* __restrict__ codebook,
    const float* __restrict__ xnorm, float* __restrict__ logits,
    float* __restrict__ pscore) {
  __shared__ __align__(16) unsigned short Bs[2][128][40];   // 20 KB, pad 40
  __shared__ float cn[128];
  __shared__ float xns[256];
  __shared__ float bwv[2][256];

  const int t = threadIdx.x;        // 0..511
  const int l = t & 63;
  const int w = t >> 6;             // wave 0..7
  const int cb = w & 1;             // col half
  const int m0 = (w >> 1) * 64;     // row group
  const int lr = l & 15, lq = l >> 4;
  const int blk = blockIdx.x;
  const int v0 = blk * 128;

  if (t < 256) xns[t] = xnorm[t];

  const int sn = t >> 2;            // staged codebook row 0..127
  const int sk = (t & 3) * 8;       // k offset within 32
  const float* cbp = codebook + (size_t)(v0 + sn) * H_ + sk;
  float csq = 0.f;

  f32x4 acc[4][4];
#pragma unroll
  for (int i = 0; i < 4; ++i)
#pragma unroll
    for (int j = 0; j < 4; ++j) acc[i][j] = (f32x4){0.f, 0.f, 0.f, 0.f};

  unsigned int aoff[4];
#pragma unroll
  for (int mt = 0; mt < 4; ++mt)
    aoff[mt] = (unsigned int)((m0 + mt * 16 + lr) * 32 + lq * 8);

#define LOAD_A(DST, KS)                                                           \
  {                                                                               \
    int ka = (KS) > 31 ? 31 : (KS);                                               \
    _Pragma("unroll")                                                             \
    for (int mt = 0; mt < 4; ++mt)                                                \
      DST[mt] = *reinterpret_cast<const s16x8*>(&A_img[(size_t)ka * 8192 + aoff[mt]]); \
  }

#define LOAD_CB(DA, DB, KS)                                                       \
  {                                                                               \
    int kl = (KS) > 31 ? 31 : (KS);                                               \
    DA = *reinterpret_cast<const float4*>(cbp + kl * 32);                         \
    DB = *reinterpret_cast<const float4*>(cbp + kl * 32 + 4);                     \
  }

#define CONV(BUF, X0, X1)                                                         \
  {                                                                               \
    float xv[8] = {X0.x, X0.y, X0.z, X0.w, X1.x, X1.y, X1.z, X1.w};               \
    u16x8 hv;                                                                     \
    _Pragma("unroll")                                                             \
    for (int i = 0; i < 8; ++i) { float x = xv[i]; csq += x * x; hv[i] = bf16hi(x); } \
    *reinterpret_cast<u16x8*>(&Bs[BUF][sn][sk]) = hv;                             \
  }

#define BAR()                                                                     \
  asm volatile("s_waitcnt lgkmcnt(0)" ::: "memory");                              \
  __builtin_amdgcn_s_barrier();                                                   \
  __builtin_amdgcn_sched_barrier(0);

#define STEP(KS, AU, AN, LDa, LDb, CVa, CVb)                                      \
  {                                                                               \
    LOAD_A(AN, (KS) + 1);                                                         \
    LOAD_CB(LDa, LDb, (KS) + 6);                                                  \
    s16x8 bh[4];                                                                  \
    _Pragma("unroll")                                                             \
    for (int nt = 0; nt < 4; ++nt)                                                \
      bh[nt] = *reinterpret_cast<const s16x8*>(&Bs[(KS) & 1][cb * 64 + nt * 16 + lr][lq * 8]); \
    __builtin_amdgcn_s_setprio(1);                                                \
    _Pragma("unroll")                                                             \
    for (int mt = 0; mt < 4; ++mt)                                                \
      _Pragma("unroll")                                                           \
      for (int nt = 0; nt < 4; ++nt)                                              \
        acc[mt][nt] = __builtin_amdgcn_mfma_f32_16x16x32_bf16(AU[mt], bh[nt], acc[mt][nt], 0, 0, 0); \
    __builtin_amdgcn_s_setprio(0);                                                \
    CONV(((KS) + 1) & 1, CVa, CVb);                                               \
    BAR();                                                                        \
  }

  // ---- prologue: A(0); cb(0..5) -> c0..c5; convert cb(0) -> Bs[0] ----
  s16x8 a0[4], a1[4];
  LOAD_A(a0, 0);
  float4 c0a, c0b, c1a, c1b, c2a, c2b, c3a, c3b, c4a, c4b, c5a, c5b;
  LOAD_CB(c0a, c0b, 0);
  LOAD_CB(c1a, c1b, 1);
  LOAD_CB(c2a, c2b, 2);
  LOAD_CB(c3a, c3b, 3);
  LOAD_CB(c4a, c4b, 4);
  LOAD_CB(c5a, c5b, 5);
  CONV(0, c0a, c0b);
  BAR();

  // ---- main loop: steps 0..29, 6-step unroll ----
#pragma unroll 1
  for (int ks = 0; ks < 30; ks += 6) {
    STEP(ks + 0, a0, a1, c0a, c0b, c1a, c1b);
    STEP(ks + 1, a1, a0, c1a, c1b, c2a, c2b);
    STEP(ks + 2, a0, a1, c2a, c2b, c3a, c3b);
    STEP(ks + 3, a1, a0, c3a, c3b, c4a, c4b);
    STEP(ks + 4, a0, a1, c4a, c4b, c5a, c5b);
    STEP(ks + 5, a1, a0, c5a, c5b, c0a, c0b);
  }
  // ---- peel step 30 ----
  {
    LOAD_A(a1, 31);
    s16x8 bh[4];
#pragma unroll
    for (int nt = 0; nt < 4; ++nt)
      bh[nt] = *reinterpret_cast<const s16x8*>(&Bs[0][cb * 64 + nt * 16 + lr][lq * 8]);
    __builtin_amdgcn_s_setprio(1);
#pragma unroll
    for (int mt = 0; mt < 4; ++mt)
#pragma unroll
      for (int nt = 0; nt < 4; ++nt)
        acc[mt][nt] = __builtin_amdgcn_mfma_f32_16x16x32_bf16(a0[mt], bh[nt], acc[mt][nt], 0, 0, 0);
    __builtin_amdgcn_s_setprio(0);
    CONV(1, c1a, c1b);
    BAR();
  }
  // ---- peel step 31 ----
  {
    s16x8 bh[4];
#pragma unroll
    for (int nt = 0; nt < 4; ++nt)
      bh[nt] = *reinterpret_cast<const s16x8*>(&Bs[1][cb * 64 + nt * 16 + lr][lq * 8]);
    __builtin_amdgcn_s_setprio(1);
#pragma unroll
    for (int mt = 0; mt < 4; ++mt)
#pragma unroll
      for (int nt = 0; nt < 4; ++nt)
        acc[mt][nt] = __builtin_amdgcn_mfma_f32_16x16x32_bf16(a1[mt], bh[nt], acc[mt][nt], 0, 0, 0);
    __builtin_amdgcn_s_setprio(0);
  }

  // ||c||^2: reduce the 4 k-offset threads of each staged row
  csq += __shfl_xor(csq, 1);
  csq += __shfl_xor(csq, 2);
  if ((t & 3) == 0) cn[sn] = csq;
  __syncthreads();

  // epilogue: nontemporal logits stores (no reuse before finalize's rescan;
  // keeps A_img / codebook lines resident in L2/L3)
  const float NEG = -3.402823466e38f;
#pragma unroll
  for (int mt = 0; mt < 4; ++mt) {
#pragma unroll
    for (int r = 0; r < 4; ++r) {
      int row = m0 + mt * 16 + lq * 4 + r;
      float xn = xns[row];
      float bs = NEG;
#pragma unroll
      for (int nt = 0; nt < 4; ++nt) {
        int col = cb * 64 + nt * 16 + lr;
        float sc = 2.f * acc[mt][nt][r] - cn[col];
        __builtin_nontemporal_store(sc - xn, &logits[(size_t)row * V_ + v0 + col]);
        bs = fmaxf(bs, sc);
      }
#pragma unroll
      for (int off = 1; off < 16; off <<= 1) bs = fmaxf(bs, __shfl_xor(bs, off));
      if (lr == 0) bwv[cb][row] = bs;
    }
  }
  __syncthreads();
  if (t < 256) pscore[(size_t)t * NCB + blk] = fmaxf(bwv[0][t], bwv[1][t]);
}

// ---------------- kernel 4: candidates + exact f64 rescore + gather/loss ----------------
__global__ __launch_bounds__(256) void finalize_kernel(
    const float* __restrict__ preq, const float* __restrict__ codebook,
    const float* __restrict__ logits, const float* __restrict__ xnorm,
    const float* __restrict__ pscore,
    float* __restrict__ out_idx, float* __restrict__ out_quant,
    float* __restrict__ lsum) {
  int row = blockIdx.x;
  int t = threadIdx.x;
  float m = pscore[(size_t)row * NCB + t];
#pragma unroll
  for (int off = 1; off < 64; off <<= 1) m = fmaxf(m, __shfl_xor(m, off));
  __shared__ float wm[4];
  if ((t & 63) == 0) wm[t >> 6] = m;
  __syncthreads();
  float M = fmaxf(fmaxf(wm[0], wm[1]), fmaxf(wm[2], wm[3]));
  float thr = M - xnorm[row] - DELTA2;
  __shared__ int cand[MAXCAND];
  __shared__ int ncand;
  if (t == 0) ncand = 0;
  __syncthreads();
  const float* lrow = logits + (size_t)row * V_;
#pragma unroll 4
  for (int it = 0; it < 32; ++it) {
    int c0 = it * 1024 + t * 4;
    float4 lg = *reinterpret_cast<const float4*>(lrow + c0);
    if (lg.x >= thr) { int p = atomicAdd(&ncand, 1); if (p < MAXCAND) cand[p] = c0; }
    if (lg.y >= thr) { int p = atomicAdd(&ncand, 1); if (p < MAXCAND) cand[p] = c0 + 1; }
    if (lg.z >= thr) { int p = atomicAdd(&ncand, 1); if (p < MAXCAND) cand[p] = c0 + 2; }
    if (lg.w >= thr) { int p = atomicAdd(&ncand, 1); if (p < MAXCAND) cand[p] = c0 + 3; }
  }
  __syncthreads();
  int total = ncand;
  const float* pr = preq + (size_t)row * H_;
  int idx;
  if (total <= MAXCAND) {
    __shared__ double sd[4];
    double best = -1.0e300; int bi = V_;
    for (int j = 0; j < total; ++j) {
      int c = cand[j];
      const float* cr = codebook + (size_t)c * H_;
      float4 cv = reinterpret_cast<const float4*>(cr)[t];
      float4 pv = reinterpret_cast<const float4*>(pr)[t];
      double p = (double)cv.x * (2.0 * (double)pv.x - (double)cv.x)
               + (double)cv.y * (2.0 * (double)pv.y - (double)cv.y)
               + (double)cv.z * (2.0 * (double)pv.z - (double)cv.z)
               + (double)cv.w * (2.0 * (double)pv.w - (double)cv.w);
#pragma unroll
      for (int off = 1; off < 64; off <<= 1) p += __shfl_xor(p, off);
      if ((t & 63) == 0) sd[t >> 6] = p;
      __syncthreads();
      double s = sd[0] + sd[1] + sd[2] + sd[3];
      if (s > best || (s == best && c < bi)) { best = s; bi = c; }
      __syncthreads();
    }
    idx = bi;
  } else {
    double best = -1.0e300; int bi = V_;
    for (int c = t; c < V_; c += 256) {
      const float* cr = codebook + (size_t)c * H_;
      double s = 0.0;
      for (int k = 0; k < H_; k += 4) {
        float4 cv = *reinterpret_cast<const float4*>(cr + k);
        float4 pv = *reinterpret_cast<const float4*>(pr + k);
        s += (double)cv.x * (2.0 * (double)pv.x - (double)cv.x)
           + (double)cv.y * (2.0 * (double)pv.y - (double)cv.y)
           + (double)cv.z * (2.0 * (double)pv.z - (double)cv.z)
           + (double)cv.w * (2.0 * (double)pv.w - (double)cv.w);
      }
      if (s > best || (s == best && c < bi)) { best = s; bi = c; }
    }
#pragma unroll
    for (int off = 1; off < 64; off <<= 1) {
      double os = __shfl_xor(best, off);
      int oi = __shfl_xor(bi, off);
      if (os > best || (os == best && oi < bi)) { best = os; bi = oi; }
    }
    __shared__ double fb[4]; __shared__ int fbi[4];
    if ((t & 63) == 0) { fb[t >> 6] = best; fbi[t >> 6] = bi; }
    __syncthreads();
    double b0 = fb[0]; int i0 = fbi[0];
    for (int wv = 1; wv < 4; ++wv)
      if (fb[wv] > b0 || (fb[wv] == b0 && fbi[wv] < i0)) { b0 = fb[wv]; i0 = fbi[wv]; }
    idx = i0;
  }
  if (t == 0) out_idx[row] = (float)idx;
  float4 e = reinterpret_cast<const float4*>(codebook + (size_t)idx * H_)[t];
  float4 p4 = reinterpret_cast<const float4*>(pr)[t];
  float4 q;
  q.x = p4.x + (e.x - p4.x); q.y = p4.y + (e.y - p4.y);
  q.z = p4.z + (e.z - p4.z); q.w = p4.w + (e.w - p4.w);
  reinterpret_cast<float4*>(out_quant)[row * 256 + t] = q;
  float dx = p4.x - e.x, dy = p4.y - e.y, dz = p4.z - e.z, dw = p4.w - e.w;
  float ls = dx * dx + dy * dy + dz * dz + dw * dw;
#pragma unroll
  for (int off = 1; off < 64; off <<= 1) ls += __shfl_xor(ls, off);
  __shared__ float lss[4];
  if ((t & 63) == 0) lss[t >> 6] = ls;
  __syncthreads();
  if (t == 0) lsum[row] = lss[0] + lss[1] + lss[2] + lss[3];
}

// ---------------- kernel 5: final losses ----------------
__global__ void loss_kernel(const float* __restrict__ lsum, float* __restrict__ out_loss) {
  int t = threadIdx.x;
  float s = lsum[t];
#pragma unroll
  for (int off = 1; off < 64; off <<= 1) s += __shfl_xor(s, off);
  __shared__ float a[4];
  if ((t & 63) == 0) a[t >> 6] = s;
  __syncthreads();
  if (t == 0) {
    float lv = (a[0] + a[1] + a[2] + a[3]) / (float)(ROWS * H_);
    out_loss[0] = lv; out_loss[1] = lv;
  }
}

extern "C" void kernel_launch(void* const* d_in, const int* in_sizes, int n_in,
                              void* d_out, int out_size, void* d_ws, size_t ws_size,
                              hipStream_t stream) {
  (void)in_sizes; (void)n_in; (void)out_size; (void)ws_size;
  const float* hidden   = (const float*)d_in[0];
  const int* mask       = (const int*)d_in[1];
  const float* Wp       = (const float*)d_in[2];
  const float* codebook = (const float*)d_in[3];

  float* out = (float*)d_out;
  float* out_logits = out;                        // 8388608
  float* out_idx    = out + 8388608;              // 256
  float* out_preq   = out_idx + 256;              // 262144
  float* out_quant  = out_preq + 262144;          // 262144
  float* out_loss   = out_quant + 262144;         // 2

  // Early scratch inside logits region (fully overwritten by dist_kernel later).
  float* part_pool = out_logits;                   // 64*32*1024 = 2097152 floats
  int*   cntpart   = (int*)(out_logits + 2097152); // 2048
  float* pooledT   = out_logits + 2099200;         // 32768
  int*   cnt       = (int*)(out_logits + 2131968); // 32

  // d_ws scratch (~0.8 MB)
  float* ws     = (float*)d_ws;
  float* xnorm  = ws;                              // 256
  float* pscore = ws + 256;                        // 256*256
  float* lsum   = ws + 65792;                      // 256
  unsigned short* A_img = (unsigned short*)(ws + 66048);   // 512 KB

  pool_kernel<<<dim3(B_, NCHUNK), 256, 0, stream>>>(hidden, mask, part_pool, cntpart);
  pool_reduce_kernel<<<128, 256, 0, stream>>>(part_pool, cntpart, pooledT, cnt);
  proj_kernel<<<512, 256, 0, stream>>>(Wp, pooledT, cnt, out_preq);
  aprep_kernel<<<ROWS, 256, 0, stream>>>(out_preq, A_img, xnorm);
  dist_kernel<<<NCB, 512, 0, stream>>>(A_img, codebook, xnorm, out_logits, pscore);
  finalize_kernel<<<ROWS, 256, 0, stream>>>(out_preq, codebook, out_logits, xnorm,
                                            pscore, out_idx, out_quant, lsum);
  loss_kernel<<<1, 256, 0, stream>>>(lsum, out_loss);
}